// Round 1
// baseline (7773.796 us; speedup 1.0000x reference)
//
#include <hip/hip_runtime.h>
#include <math.h>

// Problem constants (reference: B=2, S=2048, D=2048, H=16, HD=128)
#define BATCH 2
#define SEQ   2048
#define DIM   2048
#define NH    16
#define HD    128
#define QKV_N (3 * DIM)   // 6144
#define TOKENS (BATCH * SEQ)  // 4096

// ---------------------------------------------------------------------------
// Tiled fp32 GEMM: C[M,N] = A[M,K] @ B[K,N] + bias[N]
// 64x64 block tile, 256 threads, 4x4 micro-tile per thread, K-tile 16.
// All dims here are multiples of the tile sizes -> no bounds checks.
// ---------------------------------------------------------------------------
__global__ __launch_bounds__(256)
void gemm_bias_kernel(const float* __restrict__ A, const float* __restrict__ B,
                      const float* __restrict__ bias, float* __restrict__ C,
                      int M, int N, int K) {
    __shared__ __align__(16) float As[16][68];  // [k][row], pad 68 (272B rows, 16B-aligned)
    __shared__ __align__(16) float Bs[16][68];  // [k][col]

    const int tid = threadIdx.x;
    const int tx = tid & 15;       // 0..15 -> col group
    const int ty = tid >> 4;       // 0..15 -> row group
    const int bm = blockIdx.y * 64;
    const int bn = blockIdx.x * 64;

    float acc[4][4] = {};

    for (int k0 = 0; k0 < K; k0 += 16) {
        // Load A tile: 64 rows x 16 k (each thread: one float4)
        {
            const int row = tid >> 2;            // 0..63
            const int kq  = (tid & 3) * 4;       // 0,4,8,12
            const float4 av = *reinterpret_cast<const float4*>(
                &A[(size_t)(bm + row) * K + k0 + kq]);
            As[kq + 0][row] = av.x;
            As[kq + 1][row] = av.y;
            As[kq + 2][row] = av.z;
            As[kq + 3][row] = av.w;
        }
        // Load B tile: 16 k x 64 cols (each thread: one float4, coalesced)
        {
            const int row = tid >> 4;            // 0..15
            const int c4  = (tid & 15) * 4;      // 0..60
            *reinterpret_cast<float4*>(&Bs[row][c4]) =
                *reinterpret_cast<const float4*>(&B[(size_t)(k0 + row) * N + bn + c4]);
        }
        __syncthreads();

        #pragma unroll
        for (int kk = 0; kk < 16; ++kk) {
            float a[4], b[4];
            #pragma unroll
            for (int i = 0; i < 4; ++i) a[i] = As[kk][ty * 4 + i];
            #pragma unroll
            for (int j = 0; j < 4; ++j) b[j] = Bs[kk][tx * 4 + j];
            #pragma unroll
            for (int i = 0; i < 4; ++i)
                #pragma unroll
                for (int j = 0; j < 4; ++j)
                    acc[i][j] = fmaf(a[i], b[j], acc[i][j]);
        }
        __syncthreads();
    }

    #pragma unroll
    for (int i = 0; i < 4; ++i) {
        const int r = bm + ty * 4 + i;
        #pragma unroll
        for (int j = 0; j < 4; ++j) {
            const int c = bn + tx * 4 + j;
            C[(size_t)r * N + c] = acc[i][j] + bias[c];
        }
    }
}

// ---------------------------------------------------------------------------
// Causal attention, one wave (64 lanes) per query row.
// qkv layout: [b, s, 3, H, HD] flat -> token t row base = t*6144,
//   q at +h*128, k at +2048+h*128, v at +4096+h*128.
// Output written directly in [b, s, h*HD + d] layout (the (0,2,1,3) transpose).
// Two-pass softmax: score row (2048 wide) lives in 32 VGPRs per lane
// (lane covers k = lane + 64*j), then broadcast via LDS for the PV pass.
// ---------------------------------------------------------------------------
__global__ __launch_bounds__(256)
void attn_kernel(const float* __restrict__ qkv, float* __restrict__ out) {
    __shared__ __align__(16) float qs[4][HD];    // per-wave q row (2 KiB)
    __shared__ float ps[4][SEQ];                 // per-wave P row (32 KiB)

    const int tid  = threadIdx.x;
    const int lane = tid & 63;
    const int w    = tid >> 6;                   // wave id 0..3

    const int gid = blockIdx.x;                  // over BATCH*NH*(SEQ/4)
    const int qt  = gid % (SEQ / 4);
    const int h   = (gid / (SEQ / 4)) % NH;
    const int b   = gid / ((SEQ / 4) * NH);
    const int r   = qt * 4 + w;                  // query row in [0,SEQ)

    const size_t tok_base = (size_t)(b * SEQ) * QKV_N;
    const float* qptr  = qkv + tok_base + (size_t)r * QKV_N + h * HD;
    const float* kbase = qkv + tok_base + DIM     + h * HD;
    const float* vbase = qkv + tok_base + 2 * DIM + h * HD;

    // stage q into LDS (each lane writes 2 floats)
    qs[w][lane * 2]     = qptr[lane * 2];
    qs[w][lane * 2 + 1] = qptr[lane * 2 + 1];
    __syncthreads();

    const float scale = 0.088388347648318447f;   // 1/sqrt(128)

    float p[32];
    float m = -3.0e38f;
    for (int j = 0; j < 32; ++j) {
        const int kidx = lane + j * 64;
        float s = -3.0e38f;
        if (kidx <= r) {
            const float* kr = kbase + (size_t)kidx * QKV_N;
            float acc = 0.f;
            #pragma unroll
            for (int e = 0; e < HD; e += 4) {
                const float4 kv = *reinterpret_cast<const float4*>(kr + e);
                const float4 qv = *reinterpret_cast<const float4*>(&qs[w][e]);
                acc = fmaf(qv.x, kv.x, acc);
                acc = fmaf(qv.y, kv.y, acc);
                acc = fmaf(qv.z, kv.z, acc);
                acc = fmaf(qv.w, kv.w, acc);
            }
            s = acc * scale;
        }
        p[j] = s;
        m = fmaxf(m, s);
    }
    // wave-wide max (64 lanes)
    #pragma unroll
    for (int off = 32; off; off >>= 1) m = fmaxf(m, __shfl_xor(m, off));

    float l = 0.f;
    #pragma unroll
    for (int j = 0; j < 32; ++j) {
        const int kidx = lane + j * 64;
        const float e = (kidx <= r) ? __expf(p[j] - m) : 0.f;
        p[j] = e;
        l += e;
    }
    #pragma unroll
    for (int off = 32; off; off >>= 1) l += __shfl_xor(l, off);

    // publish P row to LDS
    #pragma unroll
    for (int j = 0; j < 32; ++j) ps[w][lane + j * 64] = p[j];
    __syncthreads();

    // PV: lane owns output dims d0 = 2*lane, 2*lane+1
    const int d0 = lane * 2;
    const float* vp = vbase + d0;
    float o0 = 0.f, o1 = 0.f;
    const int nk = r + 1;
    int k = 0;
    for (; k + 4 <= nk; k += 4) {
        #pragma unroll
        for (int u = 0; u < 4; ++u) {
            const float pv = ps[w][k + u];
            const float2 vv = *reinterpret_cast<const float2*>(vp + (size_t)(k + u) * QKV_N);
            o0 = fmaf(pv, vv.x, o0);
            o1 = fmaf(pv, vv.y, o1);
        }
    }
    for (; k < nk; ++k) {
        const float pv = ps[w][k];
        const float2 vv = *reinterpret_cast<const float2*>(vp + (size_t)k * QKV_N);
        o0 = fmaf(pv, vv.x, o0);
        o1 = fmaf(pv, vv.y, o1);
    }

    const float inv = 1.f / l;
    float* op = out + (size_t)(b * SEQ + r) * DIM + h * HD + d0;
    op[0] = o0 * inv;
    op[1] = o1 * inv;
}

// ---------------------------------------------------------------------------
// Launch
// ---------------------------------------------------------------------------
extern "C" void kernel_launch(void* const* d_in, const int* in_sizes, int n_in,
                              void* d_out, int out_size, void* d_ws, size_t ws_size,
                              hipStream_t stream) {
    const float* x      = (const float*)d_in[0];  // [2,2048,2048]
    const float* W_qkv  = (const float*)d_in[1];  // [2048,6144]
    const float* b_qkv  = (const float*)d_in[2];  // [6144]
    const float* W_proj = (const float*)d_in[3];  // [2048,2048]
    const float* b_proj = (const float*)d_in[4];  // [2048]
    // d_in[5] = mask: causal, applied analytically.

    float* out = (float*)d_out;

    // workspace: qkv [4096,6144] fp32 (96 MiB) + attn_out [4096,2048] fp32 (32 MiB)
    float* qkv      = (float*)d_ws;
    float* attn_out = qkv + (size_t)TOKENS * QKV_N;

    // 1) qkv = x @ W_qkv + b_qkv   (M=4096, N=6144, K=2048)
    {
        dim3 grid(QKV_N / 64, TOKENS / 64);
        gemm_bias_kernel<<<grid, 256, 0, stream>>>(x, W_qkv, b_qkv, qkv,
                                                   TOKENS, QKV_N, DIM);
    }
    // 2) causal attention -> attn_out [4096, 2048] in (b,s,h*hd) layout
    {
        dim3 grid(BATCH * NH * (SEQ / 4));
        attn_kernel<<<grid, 256, 0, stream>>>(qkv, attn_out);
    }
    // 3) out = attn_out @ W_proj + b_proj   (M=4096, N=2048, K=2048)
    {
        dim3 grid(DIM / 64, TOKENS / 64);
        gemm_bias_kernel<<<grid, 256, 0, stream>>>(attn_out, W_proj, b_proj, out,
                                                   TOKENS, DIM, DIM);
    }
}

// Round 2
// 1853.479 us; speedup vs baseline: 4.1942x; 4.1942x over previous
//
#include <hip/hip_runtime.h>
#include <hip/hip_bf16.h>
#include <math.h>

// Problem constants (reference: B=2, S=2048, D=2048, H=16, HD=128)
#define BATCH 2
#define SEQ   2048
#define DIM   2048
#define NH    16
#define HD    128
#define QKV_N (3 * DIM)       // 6144
#define TOKENS (BATCH * SEQ)  // 4096

typedef __attribute__((ext_vector_type(8))) short bf16x8;
typedef __attribute__((ext_vector_type(4))) float f32x4;

__device__ __forceinline__ short f2bf(float x) {
    unsigned u = __float_as_uint(x);
    u += 0x7fffu + ((u >> 16) & 1u);   // round-to-nearest-even (finite inputs)
    return (short)(u >> 16);
}

// ---------------------------------------------------------------------------
// Tiled fp32 GEMM: C[M,N] = A[M,K] @ B[K,N] + bias[N]
// 64x64 block tile, 256 threads, 4x4 micro-tile, K-tile 16.
// BF16OUT: emit bf16 (for qkv feeding the MFMA attention).
// ---------------------------------------------------------------------------
template <bool BF16OUT>
__global__ __launch_bounds__(256)
void gemm_bias_kernel(const float* __restrict__ A, const float* __restrict__ B,
                      const float* __restrict__ bias, void* __restrict__ Cv,
                      int M, int N, int K) {
    __shared__ __align__(16) float As[16][68];
    __shared__ __align__(16) float Bs[16][68];

    const int tid = threadIdx.x;
    const int tx = tid & 15;
    const int ty = tid >> 4;
    const int bm = blockIdx.y * 64;
    const int bn = blockIdx.x * 64;

    float acc[4][4] = {};

    for (int k0 = 0; k0 < K; k0 += 16) {
        {
            const int row = tid >> 2;
            const int kq  = (tid & 3) * 4;
            const float4 av = *reinterpret_cast<const float4*>(
                &A[(size_t)(bm + row) * K + k0 + kq]);
            As[kq + 0][row] = av.x;
            As[kq + 1][row] = av.y;
            As[kq + 2][row] = av.z;
            As[kq + 3][row] = av.w;
        }
        {
            const int row = tid >> 4;
            const int c4  = (tid & 15) * 4;
            *reinterpret_cast<float4*>(&Bs[row][c4]) =
                *reinterpret_cast<const float4*>(&B[(size_t)(k0 + row) * N + bn + c4]);
        }
        __syncthreads();

        #pragma unroll
        for (int kk = 0; kk < 16; ++kk) {
            float a[4], b[4];
            #pragma unroll
            for (int i = 0; i < 4; ++i) a[i] = As[kk][ty * 4 + i];
            #pragma unroll
            for (int j = 0; j < 4; ++j) b[j] = Bs[kk][tx * 4 + j];
            #pragma unroll
            for (int i = 0; i < 4; ++i)
                #pragma unroll
                for (int j = 0; j < 4; ++j)
                    acc[i][j] = fmaf(a[i], b[j], acc[i][j]);
        }
        __syncthreads();
    }

    #pragma unroll
    for (int i = 0; i < 4; ++i) {
        const int r = bm + ty * 4 + i;
        #pragma unroll
        for (int j = 0; j < 4; ++j) {
            const int c = bn + tx * 4 + j;
            const float v = acc[i][j] + bias[c];
            if (BF16OUT) {
                ((short*)Cv)[(size_t)r * N + c] = f2bf(v);
            } else {
                ((float*)Cv)[(size_t)r * N + c] = v;
            }
        }
    }
}

// ---------------------------------------------------------------------------
// MFMA flash attention (bf16 inputs, fp32 accum).
// Grid: B*NH*(SEQ/64) blocks, 256 threads (4 waves). Block handles a 64-row
// Q tile of one (b,h); wave w owns Q rows [w*16, w*16+16).
// mfma_f32_16x16x32_bf16 layouts:
//   A: lane holds A[lane&15][(lane>>4)*8 + j]   (8 contiguous k, 16B)
//   B: lane holds B[(lane>>4)*8 + j][lane&15]
//   D: lane holds D[(lane>>4)*4 + j][lane&15]
// K tile [64][128] and V^T tile [128][64] staged in LDS, XOR-swizzled
// on 16B chunks so the stride-256B/128B fragment reads are <=2-way.
// ---------------------------------------------------------------------------
__device__ __forceinline__ int swz8(int row) {   // units: shorts (8 shorts = 16B chunk)
    return ((row ^ (row >> 2)) & 7) << 3;
}

__global__ __launch_bounds__(256)
void attn_mfma_kernel(const short* __restrict__ qkv, float* __restrict__ out) {
    __shared__ short K_lds[64 * 128];    // 16 KiB
    __shared__ short VT_lds[128 * 64];   // 16 KiB  (VT[d][kv])
    __shared__ short P_lds[4 * 16 * 64]; // 8 KiB   (per-wave P tile)

    const int tid  = threadIdx.x;
    const int lane = tid & 63;
    const int w    = tid >> 6;

    // descending-qt order for causal load balance
    const int z    = blockIdx.x;                 // 0..1023
    const int qblk = (SEQ / 64 - 1) - (z >> 5);  // 31..0
    const int bh   = z & 31;
    const int h    = bh & 15;
    const int b    = bh >> 4;

    const int q0 = qblk * 64;
    const size_t tokbase = (size_t)b * SEQ * QKV_N;

    // Q fragments: 4 k-steps of 32, held in registers for the whole block
    const int lr  = lane & 15;        // fragment row/col index
    const int lhi = lane >> 4;        // fragment k-group
    const int qrow = q0 + w * 16 + lr;
    const short* qrowp = qkv + tokbase + (size_t)qrow * QKV_N + h * HD;
    bf16x8 qfrag[4];
    #pragma unroll
    for (int ks = 0; ks < 4; ++ks)
        qfrag[ks] = *reinterpret_cast<const bf16x8*>(qrowp + ks * 32 + lhi * 8);

    f32x4 o[8] = {};                  // O accumulator: 8 col-groups x 4 rows
    float m[4], l[4];
    #pragma unroll
    for (int j = 0; j < 4; ++j) { m[j] = -3.0e38f; l[j] = 0.f; }

    const float scale = 0.08838834764831845f;    // 1/sqrt(128)
    const int wq0 = q0 + w * 16;
    const int ntiles = qblk + 1;

    for (int t = 0; t < ntiles; ++t) {
        // ---- stage K tile and V^T tile (cooperative, swizzled) ----
        {
            const int r  = tid >> 2;            // 0..63 (kv row in tile)
            const int q4 = tid & 3;             // 0..3  (32-col segment)
            const size_t rowb = tokbase + (size_t)(t * 64 + r) * QKV_N + h * HD + q4 * 32;
            const short* krow = qkv + rowb + DIM;
            const short* vrow = qkv + rowb + 2 * DIM;
            short* kdst = &K_lds[r * 128];
            #pragma unroll
            for (int cc = 0; cc < 4; ++cc) {
                bf16x8 kv8 = *reinterpret_cast<const bf16x8*>(krow + cc * 8);
                *reinterpret_cast<bf16x8*>(kdst + ((q4 * 32 + cc * 8) ^ swz8(r))) = kv8;
            }
            #pragma unroll
            for (int cc = 0; cc < 4; ++cc) {
                bf16x8 vv8 = *reinterpret_cast<const bf16x8*>(vrow + cc * 8);
                #pragma unroll
                for (int j = 0; j < 8; ++j) {
                    const int d = q4 * 32 + cc * 8 + j;
                    VT_lds[d * 64 + (r ^ swz8(d))] = vv8[j];
                }
            }
        }
        __syncthreads();

        // ---- QK^T: S[16][64] = Q[16][128] . K[64][128]^T ----
        f32x4 s[4] = {};
        #pragma unroll
        for (int ks = 0; ks < 4; ++ks) {
            #pragma unroll
            for (int cg = 0; cg < 4; ++cg) {
                const int row = cg * 16 + lr;
                const bf16x8 kf = *reinterpret_cast<const bf16x8*>(
                    &K_lds[row * 128 + ((ks * 32 + lhi * 8) ^ swz8(row))]);
                s[cg] = __builtin_amdgcn_mfma_f32_16x16x32_bf16(qfrag[ks], kf, s[cg], 0, 0, 0);
            }
        }

        // ---- scale + causal mask + online softmax (per D-frag row) ----
        #pragma unroll
        for (int j = 0; j < 4; ++j) {
            const int qg = wq0 + lhi * 4 + j;
            float mx = -3.0e38f;
            #pragma unroll
            for (int cg = 0; cg < 4; ++cg) {
                const int kvg = t * 64 + cg * 16 + lr;
                float sv = s[cg][j] * scale;
                if (kvg > qg) sv = -3.0e38f;
                s[cg][j] = sv;
                mx = fmaxf(mx, sv);
            }
            #pragma unroll
            for (int off = 1; off < 16; off <<= 1) mx = fmaxf(mx, __shfl_xor(mx, off));
            const float mnew = fmaxf(m[j], mx);
            const float corr = __expf(m[j] - mnew);
            m[j] = mnew;
            float rsum = 0.f;
            #pragma unroll
            for (int cg = 0; cg < 4; ++cg) {
                const float e = __expf(s[cg][j] - mnew);
                s[cg][j] = e;          // reuse s as P
                rsum += e;
            }
            #pragma unroll
            for (int off = 1; off < 16; off <<= 1) rsum += __shfl_xor(rsum, off);
            l[j] = l[j] * corr + rsum;
            #pragma unroll
            for (int cg = 0; cg < 8; ++cg) o[cg][j] *= corr;
        }

        // ---- P -> LDS (bf16, swizzled), re-read as A fragments ----
        short* pbase = &P_lds[w * 1024];
        #pragma unroll
        for (int cg = 0; cg < 4; ++cg) {
            #pragma unroll
            for (int j = 0; j < 4; ++j) {
                const int rw = lhi * 4 + j;
                const int c  = cg * 16 + lr;
                pbase[rw * 64 + (c ^ swz8(rw))] = f2bf(s[cg][j]);
            }
        }
        bf16x8 pa[2];
        #pragma unroll
        for (int ks = 0; ks < 2; ++ks)
            pa[ks] = *reinterpret_cast<const bf16x8*>(
                &pbase[lr * 64 + ((ks * 32 + lhi * 8) ^ swz8(lr))]);

        // ---- PV: O[16][128] += P[16][64] . V[64][128] ----
        #pragma unroll
        for (int cg = 0; cg < 8; ++cg) {
            #pragma unroll
            for (int ks = 0; ks < 2; ++ks) {
                const int d = cg * 16 + lr;
                const bf16x8 vf = *reinterpret_cast<const bf16x8*>(
                    &VT_lds[d * 64 + ((ks * 32 + lhi * 8) ^ swz8(d))]);
                o[cg] = __builtin_amdgcn_mfma_f32_16x16x32_bf16(pa[ks], vf, o[cg], 0, 0, 0);
            }
        }
        __syncthreads();
    }

    // ---- epilogue: normalize, write fp32 in (b,s,h*HD+d) layout ----
    #pragma unroll
    for (int j = 0; j < 4; ++j) {
        const float inv = 1.f / l[j];
        const int qg = q0 + w * 16 + lhi * 4 + j;
        float* op = out + (size_t)(b * SEQ + qg) * DIM + h * HD;
        #pragma unroll
        for (int cg = 0; cg < 8; ++cg)
            op[cg * 16 + lr] = o[cg][j] * inv;
    }
}

// ---------------------------------------------------------------------------
// Launch
// ---------------------------------------------------------------------------
extern "C" void kernel_launch(void* const* d_in, const int* in_sizes, int n_in,
                              void* d_out, int out_size, void* d_ws, size_t ws_size,
                              hipStream_t stream) {
    const float* x      = (const float*)d_in[0];
    const float* W_qkv  = (const float*)d_in[1];
    const float* b_qkv  = (const float*)d_in[2];
    const float* W_proj = (const float*)d_in[3];
    const float* b_proj = (const float*)d_in[4];
    // d_in[5] = mask: causal, applied analytically.

    float* out = (float*)d_out;

    // ws: qkv bf16 [4096][6144] (48 MiB) + attn_out fp32 [4096][2048] (32 MiB)
    short* qkv      = (short*)d_ws;
    float* attn_out = (float*)((char*)d_ws + (size_t)TOKENS * QKV_N * sizeof(short));

    // 1) qkv = x @ W_qkv + b_qkv  -> bf16
    {
        dim3 grid(QKV_N / 64, TOKENS / 64);
        gemm_bias_kernel<true><<<grid, 256, 0, stream>>>(x, W_qkv, b_qkv, (void*)qkv,
                                                         TOKENS, QKV_N, DIM);
    }
    // 2) causal MFMA flash attention -> attn_out fp32 [4096][2048]
    {
        dim3 grid(BATCH * NH * (SEQ / 64));
        attn_mfma_kernel<<<grid, 256, 0, stream>>>(qkv, attn_out);
    }
    // 3) out = attn_out @ W_proj + b_proj  (fp32)
    {
        dim3 grid(DIM / 64, TOKENS / 64);
        gemm_bias_kernel<false><<<grid, 256, 0, stream>>>(attn_out, W_proj, b_proj,
                                                          (void*)out, TOKENS, DIM, DIM);
    }
}

// Round 3
// 334.235 us; speedup vs baseline: 23.2585x; 5.5454x over previous
//
#include <hip/hip_runtime.h>
#include <hip/hip_bf16.h>
#include <math.h>

// Problem constants (reference: B=2, S=2048, D=2048, H=16, HD=128)
#define BATCH 2
#define SEQ   2048
#define DIM   2048
#define NH    16
#define HD    128
#define QKV_N (3 * DIM)       // 6144
#define TOKENS (BATCH * SEQ)  // 4096

typedef __attribute__((ext_vector_type(8))) short bf16x8;
typedef __attribute__((ext_vector_type(4))) float f32x4;

typedef __attribute__((address_space(1))) const void* as1cv;
typedef __attribute__((address_space(3))) void* as3v;

__device__ __forceinline__ short f2bf(float x) {
    unsigned u = __float_as_uint(x);
    u += 0x7fffu + ((u >> 16) & 1u);   // round-to-nearest-even (finite inputs)
    return (short)(u >> 16);
}

__device__ __forceinline__ void gload16(const short* g, short* lds) {
    // 16B per lane; LDS dest = wave-uniform base + lane*16 (HW). Source is per-lane.
    __builtin_amdgcn_global_load_lds((as1cv)g, (as3v)lds, 16, 0, 0);
}

// ---------------------------------------------------------------------------
// fp32 -> bf16 elementwise cast (x). Exact-cover grid, 8 elems/thread.
// ---------------------------------------------------------------------------
__global__ __launch_bounds__(256)
void f32_to_bf16_kernel(const float* __restrict__ in, short* __restrict__ out) {
    const size_t i = ((size_t)blockIdx.x * 256 + threadIdx.x) * 8;
    const float4 a = *reinterpret_cast<const float4*>(in + i);
    const float4 b = *reinterpret_cast<const float4*>(in + i + 4);
    bf16x8 v;
    v[0] = f2bf(a.x); v[1] = f2bf(a.y); v[2] = f2bf(a.z); v[3] = f2bf(a.w);
    v[4] = f2bf(b.x); v[5] = f2bf(b.y); v[6] = f2bf(b.z); v[7] = f2bf(b.w);
    *reinterpret_cast<bf16x8*>(out + i) = v;
}

// ---------------------------------------------------------------------------
// fp32 [K][N] -> bf16 [N][K] tiled transpose+cast (weights).
// 64x64 tile, LDS float[64][65] (pad kills bank conflicts both directions).
// ---------------------------------------------------------------------------
__global__ __launch_bounds__(256)
void transpose_f32_to_bf16(const float* __restrict__ W, short* __restrict__ Wt,
                           int K, int N) {
    __shared__ float t[64][65];
    const int tid = threadIdx.x;
    const int n0 = blockIdx.x * 64;
    const int k0 = blockIdx.y * 64;
    const int tc = tid & 63, tr = tid >> 6;
    #pragma unroll
    for (int i = 0; i < 16; ++i)
        t[tr + i * 4][tc] = W[(size_t)(k0 + tr + i * 4) * N + n0 + tc];
    __syncthreads();
    #pragma unroll
    for (int i = 0; i < 16; ++i)
        Wt[(size_t)(n0 + tr + i * 4) * K + k0 + tc] = f2bf(t[tc][tr + i * 4]);
}

// ---------------------------------------------------------------------------
// bf16 MFMA GEMM: C[M,N] = A[M,K] @ Bt[N,K]^T + bias[N]   (m97-ladder structure)
// 128x128 tile, BK=64, 256 threads / 4 waves (2x2 of 64x64), acc 4x4 frags.
// Staging: global_load_lds width-16, linear LDS dest, XOR-swizzled source
// chunks; ds_read_b128 with the same XOR -> conflict-free (rule #21).
// ---------------------------------------------------------------------------
template <bool BF16OUT>
__global__ __launch_bounds__(256)
void gemm_mfma_kernel(const short* __restrict__ A, const short* __restrict__ Bt,
                      const float* __restrict__ bias, void* __restrict__ Cv,
                      int M, int N, int K, int nM) {
    __shared__ short A_lds[128 * 64];   // [row][k] shorts, 16 KiB
    __shared__ short B_lds[128 * 64];   // [col][k] shorts, 16 KiB

    const int tid  = threadIdx.x;
    const int lane = tid & 63;
    const int w    = tid >> 6;
    const int lr   = lane & 15;
    const int lhi  = lane >> 4;
    const int wr   = w >> 1;
    const int wc   = w & 1;

    // XCD-bijective swizzle (caller guarantees gridDim.x % 8 == 0)
    const int nwg  = gridDim.x;
    const int cpx  = nwg >> 3;
    const int orig = blockIdx.x;
    const int wg   = (orig & 7) * cpx + (orig >> 3);
    const int bm   = (wg % nM) * 128;
    const int bn   = (wg / nM) * 128;

    // staging: issue i stages rows [i*32, i*32+32), thread -> (row, 16B chunk)
    const int srow   = tid >> 3;                   // 0..31
    const int schunk = (tid & 7) ^ (srow & 7);     // inverse-swizzled source chunk
    const short* gA = A  + (size_t)(bm + srow) * K + schunk * 8;
    const short* gB = Bt + (size_t)(bn + srow) * K + schunk * 8;
    short* ldsA = A_lds + w * 512;                 // wave-uniform base (+lane*8 by HW)
    short* ldsB = B_lds + w * 512;

    f32x4 acc[4][4] = {};

    for (int k0 = 0; k0 < K; k0 += 64) {
        #pragma unroll
        for (int i = 0; i < 4; ++i)
            gload16(gA + (size_t)(i * 32) * K + k0, ldsA + i * 2048);
        #pragma unroll
        for (int i = 0; i < 4; ++i)
            gload16(gB + (size_t)(i * 32) * K + k0, ldsB + i * 2048);
        __syncthreads();   // drains vmcnt; staged tile visible

        #pragma unroll
        for (int ks = 0; ks < 2; ++ks) {
            const int cb = ks * 4 + lhi;           // logical 16B chunk in row
            bf16x8 af[4], bfr[4];
            #pragma unroll
            for (int mi = 0; mi < 4; ++mi) {
                const int r = wr * 64 + mi * 16 + lr;
                af[mi] = *reinterpret_cast<const bf16x8*>(
                    &A_lds[r * 64 + ((cb ^ (r & 7)) << 3)]);
            }
            #pragma unroll
            for (int ni = 0; ni < 4; ++ni) {
                const int c = wc * 64 + ni * 16 + lr;
                bfr[ni] = *reinterpret_cast<const bf16x8*>(
                    &B_lds[c * 64 + ((cb ^ (c & 7)) << 3)]);
            }
            #pragma unroll
            for (int mi = 0; mi < 4; ++mi)
                #pragma unroll
                for (int ni = 0; ni < 4; ++ni)
                    acc[mi][ni] = __builtin_amdgcn_mfma_f32_16x16x32_bf16(
                        af[mi], bfr[ni], acc[mi][ni], 0, 0, 0);
        }
        __syncthreads();   // protect LDS before next stage
    }

    // epilogue: D row=(lane>>4)*4+j, col=lane&15 (verified layout)
    #pragma unroll
    for (int mi = 0; mi < 4; ++mi) {
        #pragma unroll
        for (int j = 0; j < 4; ++j) {
            const int r = bm + wr * 64 + mi * 16 + lhi * 4 + j;
            #pragma unroll
            for (int ni = 0; ni < 4; ++ni) {
                const int c = bn + wc * 64 + ni * 16 + lr;
                const float v = acc[mi][ni][j] + bias[c];
                if (BF16OUT) ((short*)Cv)[(size_t)r * N + c] = f2bf(v);
                else         ((float*)Cv)[(size_t)r * N + c] = v;
            }
        }
    }
}

// ---------------------------------------------------------------------------
// MFMA flash attention (bf16 in/out, fp32 accum). Same as round 2 except
// the output is bf16 (feeds the bf16 proj GEMM directly).
// ---------------------------------------------------------------------------
__device__ __forceinline__ int swz8(int row) {   // units: shorts (8 = 16B chunk)
    return ((row ^ (row >> 2)) & 7) << 3;
}

__global__ __launch_bounds__(256)
void attn_mfma_kernel(const short* __restrict__ qkv, short* __restrict__ out) {
    __shared__ short K_lds[64 * 128];    // 16 KiB
    __shared__ short VT_lds[128 * 64];   // 16 KiB  (VT[d][kv])
    __shared__ short P_lds[4 * 16 * 64]; // 8 KiB   (per-wave P tile)

    const int tid  = threadIdx.x;
    const int lane = tid & 63;
    const int w    = tid >> 6;

    const int z    = blockIdx.x;                 // 0..1023
    const int qblk = (SEQ / 64 - 1) - (z >> 5);  // descending for load balance
    const int bh   = z & 31;
    const int h    = bh & 15;
    const int b    = bh >> 4;

    const int q0 = qblk * 64;
    const size_t tokbase = (size_t)b * SEQ * QKV_N;

    const int lr  = lane & 15;
    const int lhi = lane >> 4;
    const int qrow = q0 + w * 16 + lr;
    const short* qrowp = qkv + tokbase + (size_t)qrow * QKV_N + h * HD;
    bf16x8 qfrag[4];
    #pragma unroll
    for (int ks = 0; ks < 4; ++ks)
        qfrag[ks] = *reinterpret_cast<const bf16x8*>(qrowp + ks * 32 + lhi * 8);

    f32x4 o[8] = {};
    float m[4], l[4];
    #pragma unroll
    for (int j = 0; j < 4; ++j) { m[j] = -3.0e38f; l[j] = 0.f; }

    const float scale = 0.08838834764831845f;    // 1/sqrt(128)
    const int wq0 = q0 + w * 16;
    const int ntiles = qblk + 1;

    for (int t = 0; t < ntiles; ++t) {
        {
            const int r  = tid >> 2;
            const int q4 = tid & 3;
            const size_t rowb = tokbase + (size_t)(t * 64 + r) * QKV_N + h * HD + q4 * 32;
            const short* krow = qkv + rowb + DIM;
            const short* vrow = qkv + rowb + 2 * DIM;
            short* kdst = &K_lds[r * 128];
            #pragma unroll
            for (int cc = 0; cc < 4; ++cc) {
                bf16x8 kv8 = *reinterpret_cast<const bf16x8*>(krow + cc * 8);
                *reinterpret_cast<bf16x8*>(kdst + ((q4 * 32 + cc * 8) ^ swz8(r))) = kv8;
            }
            #pragma unroll
            for (int cc = 0; cc < 4; ++cc) {
                bf16x8 vv8 = *reinterpret_cast<const bf16x8*>(vrow + cc * 8);
                #pragma unroll
                for (int j = 0; j < 8; ++j) {
                    const int d = q4 * 32 + cc * 8 + j;
                    VT_lds[d * 64 + (r ^ swz8(d))] = vv8[j];
                }
            }
        }
        __syncthreads();

        f32x4 s[4] = {};
        #pragma unroll
        for (int ks = 0; ks < 4; ++ks) {
            #pragma unroll
            for (int cg = 0; cg < 4; ++cg) {
                const int row = cg * 16 + lr;
                const bf16x8 kf = *reinterpret_cast<const bf16x8*>(
                    &K_lds[row * 128 + ((ks * 32 + lhi * 8) ^ swz8(row))]);
                s[cg] = __builtin_amdgcn_mfma_f32_16x16x32_bf16(qfrag[ks], kf, s[cg], 0, 0, 0);
            }
        }

        #pragma unroll
        for (int j = 0; j < 4; ++j) {
            const int qg = wq0 + lhi * 4 + j;
            float mx = -3.0e38f;
            #pragma unroll
            for (int cg = 0; cg < 4; ++cg) {
                const int kvg = t * 64 + cg * 16 + lr;
                float sv = s[cg][j] * scale;
                if (kvg > qg) sv = -3.0e38f;
                s[cg][j] = sv;
                mx = fmaxf(mx, sv);
            }
            #pragma unroll
            for (int off = 1; off < 16; off <<= 1) mx = fmaxf(mx, __shfl_xor(mx, off));
            const float mnew = fmaxf(m[j], mx);
            const float corr = __expf(m[j] - mnew);
            m[j] = mnew;
            float rsum = 0.f;
            #pragma unroll
            for (int cg = 0; cg < 4; ++cg) {
                const float e = __expf(s[cg][j] - mnew);
                s[cg][j] = e;
                rsum += e;
            }
            #pragma unroll
            for (int off = 1; off < 16; off <<= 1) rsum += __shfl_xor(rsum, off);
            l[j] = l[j] * corr + rsum;
            #pragma unroll
            for (int cg = 0; cg < 8; ++cg) o[cg][j] *= corr;
        }

        short* pbase = &P_lds[w * 1024];
        #pragma unroll
        for (int cg = 0; cg < 4; ++cg) {
            #pragma unroll
            for (int j = 0; j < 4; ++j) {
                const int rw = lhi * 4 + j;
                const int c  = cg * 16 + lr;
                pbase[rw * 64 + (c ^ swz8(rw))] = f2bf(s[cg][j]);
            }
        }
        bf16x8 pa[2];
        #pragma unroll
        for (int ks = 0; ks < 2; ++ks)
            pa[ks] = *reinterpret_cast<const bf16x8*>(
                &pbase[lr * 64 + ((ks * 32 + lhi * 8) ^ swz8(lr))]);

        #pragma unroll
        for (int cg = 0; cg < 8; ++cg) {
            #pragma unroll
            for (int ks = 0; ks < 2; ++ks) {
                const int d = cg * 16 + lr;
                const bf16x8 vf = *reinterpret_cast<const bf16x8*>(
                    &VT_lds[d * 64 + ((ks * 32 + lhi * 8) ^ swz8(d))]);
                o[cg] = __builtin_amdgcn_mfma_f32_16x16x32_bf16(pa[ks], vf, o[cg], 0, 0, 0);
            }
        }
        __syncthreads();
    }

    #pragma unroll
    for (int j = 0; j < 4; ++j) {
        const float inv = 1.f / l[j];
        const int qg = q0 + w * 16 + lhi * 4 + j;
        short* op = out + (size_t)(b * SEQ + qg) * DIM + h * HD;
        #pragma unroll
        for (int cg = 0; cg < 8; ++cg)
            op[cg * 16 + lr] = f2bf(o[cg][j] * inv);
    }
}

// ---------------------------------------------------------------------------
// Launch
// ---------------------------------------------------------------------------
extern "C" void kernel_launch(void* const* d_in, const int* in_sizes, int n_in,
                              void* d_out, int out_size, void* d_ws, size_t ws_size,
                              hipStream_t stream) {
    const float* x      = (const float*)d_in[0];
    const float* W_qkv  = (const float*)d_in[1];
    const float* b_qkv  = (const float*)d_in[2];
    const float* W_proj = (const float*)d_in[3];
    const float* b_proj = (const float*)d_in[4];
    // d_in[5] = mask: causal, applied analytically.

    float* out = (float*)d_out;

    // ws layout (bf16 shorts): qkv 48MiB | attn_out 16MiB | x 16MiB | WqkvT 24MiB | WprojT 8MiB
    short* qkv_bf  = (short*)d_ws;
    short* attn_bf = qkv_bf  + (size_t)TOKENS * QKV_N;
    short* x_bf    = attn_bf + (size_t)TOKENS * DIM;
    short* wqkv_t  = x_bf    + (size_t)TOKENS * DIM;
    short* wproj_t = wqkv_t  + (size_t)DIM * QKV_N;

    // 0) casts / transposes
    f32_to_bf16_kernel<<<TOKENS * DIM / (256 * 8), 256, 0, stream>>>(x, x_bf);
    {
        dim3 g(QKV_N / 64, DIM / 64);
        transpose_f32_to_bf16<<<g, 256, 0, stream>>>(W_qkv, wqkv_t, DIM, QKV_N);
    }
    {
        dim3 g(DIM / 64, DIM / 64);
        transpose_f32_to_bf16<<<g, 256, 0, stream>>>(W_proj, wproj_t, DIM, DIM);
    }

    // 1) qkv = x @ W_qkv + b_qkv  (bf16 MFMA, bf16 out)
    {
        const int nM = TOKENS / 128, nN = QKV_N / 128;   // 32 x 48 = 1536
        gemm_mfma_kernel<true><<<nM * nN, 256, 0, stream>>>(
            x_bf, wqkv_t, b_qkv, (void*)qkv_bf, TOKENS, QKV_N, DIM, nM);
    }
    // 2) causal MFMA flash attention -> bf16 [4096][2048]
    attn_mfma_kernel<<<BATCH * NH * (SEQ / 64), 256, 0, stream>>>(qkv_bf, attn_bf);

    // 3) out = attn_out @ W_proj + b_proj  (bf16 MFMA, fp32 out)
    {
        const int nM = TOKENS / 128, nN = DIM / 128;     // 32 x 16 = 512
        gemm_mfma_kernel<false><<<nM * nN, 256, 0, stream>>>(
            attn_bf, wproj_t, b_proj, (void*)out, TOKENS, DIM, DIM, nM);
    }
}

// Round 4
// 284.519 us; speedup vs baseline: 27.3226x; 1.1747x over previous
//
#include <hip/hip_runtime.h>
#include <hip/hip_bf16.h>
#include <math.h>

// Problem constants (reference: B=2, S=2048, D=2048, H=16, HD=128)
#define BATCH 2
#define SEQ   2048
#define DIM   2048
#define NH    16
#define HD    128
#define QKV_N (3 * DIM)       // 6144
#define TOKENS (BATCH * SEQ)  // 4096

typedef __attribute__((ext_vector_type(8))) short bf16x8;
typedef __attribute__((ext_vector_type(4))) float f32x4;

typedef __attribute__((address_space(1))) const void* as1cv;
typedef __attribute__((address_space(3))) void* as3v;

__device__ __forceinline__ short f2bf(float x) {
    unsigned u = __float_as_uint(x);
    u += 0x7fffu + ((u >> 16) & 1u);   // round-to-nearest-even (finite inputs)
    return (short)(u >> 16);
}

__device__ __forceinline__ void gload16(const short* g, short* lds) {
    // 16B per lane; LDS dest = wave-uniform base + lane*16 (HW). Source is per-lane.
    __builtin_amdgcn_global_load_lds((as1cv)g, (as3v)lds, 16, 0, 0);
}

// ---------------------------------------------------------------------------
// fp32 -> bf16 elementwise cast (x). Exact-cover grid, 8 elems/thread.
// ---------------------------------------------------------------------------
__global__ __launch_bounds__(256)
void f32_to_bf16_kernel(const float* __restrict__ in, short* __restrict__ out) {
    const size_t i = ((size_t)blockIdx.x * 256 + threadIdx.x) * 8;
    const float4 a = *reinterpret_cast<const float4*>(in + i);
    const float4 b = *reinterpret_cast<const float4*>(in + i + 4);
    bf16x8 v;
    v[0] = f2bf(a.x); v[1] = f2bf(a.y); v[2] = f2bf(a.z); v[3] = f2bf(a.w);
    v[4] = f2bf(b.x); v[5] = f2bf(b.y); v[6] = f2bf(b.z); v[7] = f2bf(b.w);
    *reinterpret_cast<bf16x8*>(out + i) = v;
}

// ---------------------------------------------------------------------------
// fp32 [K][N] -> bf16 [N][K] tiled transpose+cast (weights).
// ---------------------------------------------------------------------------
__global__ __launch_bounds__(256)
void transpose_f32_to_bf16(const float* __restrict__ W, short* __restrict__ Wt,
                           int K, int N) {
    __shared__ float t[64][65];
    const int tid = threadIdx.x;
    const int n0 = blockIdx.x * 64;
    const int k0 = blockIdx.y * 64;
    const int tc = tid & 63, tr = tid >> 6;
    #pragma unroll
    for (int i = 0; i < 16; ++i)
        t[tr + i * 4][tc] = W[(size_t)(k0 + tr + i * 4) * N + n0 + tc];
    __syncthreads();
    #pragma unroll
    for (int i = 0; i < 16; ++i)
        Wt[(size_t)(n0 + tr + i * 4) * K + k0 + tc] = f2bf(t[tc][tr + i * 4]);
}

// ---------------------------------------------------------------------------
// bf16 MFMA GEMM: C[M,N] = A[M,K] @ Bt[N,K]^T + bias[N]
// 128x128 tile, BK=64, 256 threads / 4 waves (2x2 of 64x64), acc 4x4 frags.
// DOUBLE-BUFFERED (2x32 KiB LDS) with stage-2-ahead + counted vmcnt(8):
//   prologue: stage(t0->buf0), stage(t1->buf1), vmcnt(8), barrier
//   iter t:   ds_read 16xb128 from buf[cur]; lgkmcnt(0); sched_barrier;
//             s_barrier (reads done) -> stage(t+2 -> buf[cur]);
//             setprio(1); 32 MFMA; setprio(0);
//             vmcnt(8) (t+1 landed, t+2 in flight); s_barrier
// Never drains vmcnt to 0 in steady state (T4). Staging source chunks are
// inverse-XOR-swizzled; ds_read applies the same XOR (rule #21).
// ---------------------------------------------------------------------------
template <bool BF16OUT>
__global__ __launch_bounds__(256, 2)
void gemm_mfma_kernel(const short* __restrict__ A, const short* __restrict__ Bt,
                      const float* __restrict__ bias, void* __restrict__ Cv,
                      int M, int N, int K, int nM) {
    __shared__ short A_lds[2][128 * 64];   // 2 x 16 KiB
    __shared__ short B_lds[2][128 * 64];   // 2 x 16 KiB

    const int tid  = threadIdx.x;
    const int lane = tid & 63;
    const int w    = tid >> 6;
    const int lr   = lane & 15;
    const int lhi  = lane >> 4;
    const int wr   = w >> 1;
    const int wc   = w & 1;

    // XCD-bijective swizzle (caller guarantees gridDim.x % 8 == 0)
    const int nwg  = gridDim.x;
    const int cpx  = nwg >> 3;
    const int orig = blockIdx.x;
    const int wg   = (orig & 7) * cpx + (orig >> 3);
    const int bm   = (wg % nM) * 128;
    const int bn   = (wg / nM) * 128;

    // staging: issue i covers rows [i*32, i*32+32); thread -> (row, 16B chunk)
    const int srow   = tid >> 3;                   // 0..31
    const int schunk = (tid & 7) ^ (srow & 7);     // inverse-swizzled source chunk
    const short* gA = A  + (size_t)(bm + srow) * K + schunk * 8;
    const short* gB = Bt + (size_t)(bn + srow) * K + schunk * 8;

    const int nt = K >> 6;                         // 32 for K=2048

    // stage K-tile t into buffer buf (8 x gload16 per thread)
    auto STAGE = [&](int t, int buf) {
        const int ko = t * 64;
        short* la = &A_lds[buf][w * 512];
        short* lb = &B_lds[buf][w * 512];
        #pragma unroll
        for (int i = 0; i < 4; ++i)
            gload16(gA + (size_t)(i * 32) * K + ko, la + i * 2048);
        #pragma unroll
        for (int i = 0; i < 4; ++i)
            gload16(gB + (size_t)(i * 32) * K + ko, lb + i * 2048);
    };

    f32x4 acc[4][4] = {};

    STAGE(0, 0);
    STAGE(1, 1);
    asm volatile("s_waitcnt vmcnt(8)" ::: "memory");   // tile 0 landed
    __builtin_amdgcn_s_barrier();

    int cur = 0;
    for (int t = 0; t < nt; ++t, cur ^= 1) {
        // ---- read all fragments of tile t from buf[cur] ----
        bf16x8 af[2][4], bfr[2][4];
        const short* Ab = &A_lds[cur][0];
        const short* Bb = &B_lds[cur][0];
        #pragma unroll
        for (int ks = 0; ks < 2; ++ks) {
            const int cb = ks * 4 + lhi;
            #pragma unroll
            for (int mi = 0; mi < 4; ++mi) {
                const int r = wr * 64 + mi * 16 + lr;
                af[ks][mi] = *reinterpret_cast<const bf16x8*>(
                    &Ab[r * 64 + ((cb ^ (r & 7)) << 3)]);
            }
            #pragma unroll
            for (int ni = 0; ni < 4; ++ni) {
                const int c = wc * 64 + ni * 16 + lr;
                bfr[ks][ni] = *reinterpret_cast<const bf16x8*>(
                    &Bb[c * 64 + ((cb ^ (c & 7)) << 3)]);
            }
        }
        asm volatile("s_waitcnt lgkmcnt(0)" ::: "memory");
        __builtin_amdgcn_sched_barrier(0);
        __builtin_amdgcn_s_barrier();          // all waves done reading buf[cur]
        __builtin_amdgcn_sched_barrier(0);

        if (t + 2 < nt) STAGE(t + 2, cur);     // overwrite the buffer just read

        __builtin_amdgcn_s_setprio(1);
        #pragma unroll
        for (int ks = 0; ks < 2; ++ks)
            #pragma unroll
            for (int mi = 0; mi < 4; ++mi)
                #pragma unroll
                for (int ni = 0; ni < 4; ++ni)
                    acc[mi][ni] = __builtin_amdgcn_mfma_f32_16x16x32_bf16(
                        af[ks][mi], bfr[ks][ni], acc[mi][ni], 0, 0, 0);
        __builtin_amdgcn_s_setprio(0);
        __builtin_amdgcn_sched_barrier(0);

        if (t + 2 < nt) {
            asm volatile("s_waitcnt vmcnt(8)" ::: "memory");   // t+1 landed
            __builtin_amdgcn_s_barrier();
        } else if (t + 1 < nt) {
            asm volatile("s_waitcnt vmcnt(0)" ::: "memory");   // last tile landed
            __builtin_amdgcn_s_barrier();
        }
    }

    // epilogue: D row=(lane>>4)*4+j, col=lane&15 (verified layout)
    #pragma unroll
    for (int mi = 0; mi < 4; ++mi) {
        #pragma unroll
        for (int j = 0; j < 4; ++j) {
            const int r = bm + wr * 64 + mi * 16 + lhi * 4 + j;
            #pragma unroll
            for (int ni = 0; ni < 4; ++ni) {
                const int c = bn + wc * 64 + ni * 16 + lr;
                const float v = acc[mi][ni][j] + bias[c];
                if (BF16OUT) ((short*)Cv)[(size_t)r * N + c] = f2bf(v);
                else         ((float*)Cv)[(size_t)r * N + c] = v;
            }
        }
    }
}

// ---------------------------------------------------------------------------
// MFMA flash attention (bf16 in/out, fp32 accum). Unchanged from round 3.
// ---------------------------------------------------------------------------
__device__ __forceinline__ int swz8(int row) {   // units: shorts (8 = 16B chunk)
    return ((row ^ (row >> 2)) & 7) << 3;
}

__global__ __launch_bounds__(256)
void attn_mfma_kernel(const short* __restrict__ qkv, short* __restrict__ out) {
    __shared__ short K_lds[64 * 128];    // 16 KiB
    __shared__ short VT_lds[128 * 64];   // 16 KiB  (VT[d][kv])
    __shared__ short P_lds[4 * 16 * 64]; // 8 KiB   (per-wave P tile)

    const int tid  = threadIdx.x;
    const int lane = tid & 63;
    const int w    = tid >> 6;

    const int z    = blockIdx.x;                 // 0..1023
    const int qblk = (SEQ / 64 - 1) - (z >> 5);  // descending for load balance
    const int bh   = z & 31;
    const int h    = bh & 15;
    const int b    = bh >> 4;

    const int q0 = qblk * 64;
    const size_t tokbase = (size_t)b * SEQ * QKV_N;

    const int lr  = lane & 15;
    const int lhi = lane >> 4;
    const int qrow = q0 + w * 16 + lr;
    const short* qrowp = qkv + tokbase + (size_t)qrow * QKV_N + h * HD;
    bf16x8 qfrag[4];
    #pragma unroll
    for (int ks = 0; ks < 4; ++ks)
        qfrag[ks] = *reinterpret_cast<const bf16x8*>(qrowp + ks * 32 + lhi * 8);

    f32x4 o[8] = {};
    float m[4], l[4];
    #pragma unroll
    for (int j = 0; j < 4; ++j) { m[j] = -3.0e38f; l[j] = 0.f; }

    const float scale = 0.08838834764831845f;    // 1/sqrt(128)
    const int wq0 = q0 + w * 16;
    const int ntiles = qblk + 1;

    for (int t = 0; t < ntiles; ++t) {
        {
            const int r  = tid >> 2;
            const int q4 = tid & 3;
            const size_t rowb = tokbase + (size_t)(t * 64 + r) * QKV_N + h * HD + q4 * 32;
            const short* krow = qkv + rowb + DIM;
            const short* vrow = qkv + rowb + 2 * DIM;
            short* kdst = &K_lds[r * 128];
            #pragma unroll
            for (int cc = 0; cc < 4; ++cc) {
                bf16x8 kv8 = *reinterpret_cast<const bf16x8*>(krow + cc * 8);
                *reinterpret_cast<bf16x8*>(kdst + ((q4 * 32 + cc * 8) ^ swz8(r))) = kv8;
            }
            #pragma unroll
            for (int cc = 0; cc < 4; ++cc) {
                bf16x8 vv8 = *reinterpret_cast<const bf16x8*>(vrow + cc * 8);
                #pragma unroll
                for (int j = 0; j < 8; ++j) {
                    const int d = q4 * 32 + cc * 8 + j;
                    VT_lds[d * 64 + (r ^ swz8(d))] = vv8[j];
                }
            }
        }
        __syncthreads();

        f32x4 s[4] = {};
        #pragma unroll
        for (int ks = 0; ks < 4; ++ks) {
            #pragma unroll
            for (int cg = 0; cg < 4; ++cg) {
                const int row = cg * 16 + lr;
                const bf16x8 kf = *reinterpret_cast<const bf16x8*>(
                    &K_lds[row * 128 + ((ks * 32 + lhi * 8) ^ swz8(row))]);
                s[cg] = __builtin_amdgcn_mfma_f32_16x16x32_bf16(qfrag[ks], kf, s[cg], 0, 0, 0);
            }
        }

        #pragma unroll
        for (int j = 0; j < 4; ++j) {
            const int qg = wq0 + lhi * 4 + j;
            float mx = -3.0e38f;
            #pragma unroll
            for (int cg = 0; cg < 4; ++cg) {
                const int kvg = t * 64 + cg * 16 + lr;
                float sv = s[cg][j] * scale;
                if (kvg > qg) sv = -3.0e38f;
                s[cg][j] = sv;
                mx = fmaxf(mx, sv);
            }
            #pragma unroll
            for (int off = 1; off < 16; off <<= 1) mx = fmaxf(mx, __shfl_xor(mx, off));
            const float mnew = fmaxf(m[j], mx);
            const float corr = __expf(m[j] - mnew);
            m[j] = mnew;
            float rsum = 0.f;
            #pragma unroll
            for (int cg = 0; cg < 4; ++cg) {
                const float e = __expf(s[cg][j] - mnew);
                s[cg][j] = e;
                rsum += e;
            }
            #pragma unroll
            for (int off = 1; off < 16; off <<= 1) rsum += __shfl_xor(rsum, off);
            l[j] = l[j] * corr + rsum;
            #pragma unroll
            for (int cg = 0; cg < 8; ++cg) o[cg][j] *= corr;
        }

        short* pbase = &P_lds[w * 1024];
        #pragma unroll
        for (int cg = 0; cg < 4; ++cg) {
            #pragma unroll
            for (int j = 0; j < 4; ++j) {
                const int rw = lhi * 4 + j;
                const int c  = cg * 16 + lr;
                pbase[rw * 64 + (c ^ swz8(rw))] = f2bf(s[cg][j]);
            }
        }
        bf16x8 pa[2];
        #pragma unroll
        for (int ks = 0; ks < 2; ++ks)
            pa[ks] = *reinterpret_cast<const bf16x8*>(
                &pbase[lr * 64 + ((ks * 32 + lhi * 8) ^ swz8(lr))]);

        #pragma unroll
        for (int cg = 0; cg < 8; ++cg) {
            #pragma unroll
            for (int ks = 0; ks < 2; ++ks) {
                const int d = cg * 16 + lr;
                const bf16x8 vf = *reinterpret_cast<const bf16x8*>(
                    &VT_lds[d * 64 + ((ks * 32 + lhi * 8) ^ swz8(d))]);
                o[cg] = __builtin_amdgcn_mfma_f32_16x16x32_bf16(pa[ks], vf, o[cg], 0, 0, 0);
            }
        }
        __syncthreads();
    }

    #pragma unroll
    for (int j = 0; j < 4; ++j) {
        const float inv = 1.f / l[j];
        const int qg = q0 + w * 16 + lhi * 4 + j;
        short* op = out + (size_t)(b * SEQ + qg) * DIM + h * HD;
        #pragma unroll
        for (int cg = 0; cg < 8; ++cg)
            op[cg * 16 + lr] = f2bf(o[cg][j] * inv);
    }
}

// ---------------------------------------------------------------------------
// Launch
// ---------------------------------------------------------------------------
extern "C" void kernel_launch(void* const* d_in, const int* in_sizes, int n_in,
                              void* d_out, int out_size, void* d_ws, size_t ws_size,
                              hipStream_t stream) {
    const float* x      = (const float*)d_in[0];
    const float* W_qkv  = (const float*)d_in[1];
    const float* b_qkv  = (const float*)d_in[2];
    const float* W_proj = (const float*)d_in[3];
    const float* b_proj = (const float*)d_in[4];
    // d_in[5] = mask: causal, applied analytically.

    float* out = (float*)d_out;

    // ws layout (bf16 shorts): qkv 48MiB | attn_out 16MiB | x 16MiB | WqkvT 24MiB | WprojT 8MiB
    short* qkv_bf  = (short*)d_ws;
    short* attn_bf = qkv_bf  + (size_t)TOKENS * QKV_N;
    short* x_bf    = attn_bf + (size_t)TOKENS * DIM;
    short* wqkv_t  = x_bf    + (size_t)TOKENS * DIM;
    short* wproj_t = wqkv_t  + (size_t)DIM * QKV_N;

    // 0) casts / transposes
    f32_to_bf16_kernel<<<TOKENS * DIM / (256 * 8), 256, 0, stream>>>(x, x_bf);
    {
        dim3 g(QKV_N / 64, DIM / 64);
        transpose_f32_to_bf16<<<g, 256, 0, stream>>>(W_qkv, wqkv_t, DIM, QKV_N);
    }
    {
        dim3 g(DIM / 64, DIM / 64);
        transpose_f32_to_bf16<<<g, 256, 0, stream>>>(W_proj, wproj_t, DIM, DIM);
    }

    // 1) qkv = x @ W_qkv + b_qkv  (bf16 MFMA, bf16 out)
    {
        const int nM = TOKENS / 128, nN = QKV_N / 128;   // 32 x 48 = 1536
        gemm_mfma_kernel<true><<<nM * nN, 256, 0, stream>>>(
            x_bf, wqkv_t, b_qkv, (void*)qkv_bf, TOKENS, QKV_N, DIM, nM);
    }
    // 2) causal MFMA flash attention -> bf16 [4096][2048]
    attn_mfma_kernel<<<BATCH * NH * (SEQ / 64), 256, 0, stream>>>(qkv_bf, attn_bf);

    // 3) out = attn_out @ W_proj + b_proj  (bf16 MFMA, fp32 out)
    {
        const int nM = TOKENS / 128, nN = DIM / 128;     // 32 x 16 = 512
        gemm_mfma_kernel<false><<<nM * nN, 256, 0, stream>>>(
            attn_bf, wproj_t, b_proj, (void*)out, TOKENS, DIM, DIM, nM);
    }
}